// Round 4
// baseline (2952.710 us; speedup 1.0000x reference)
//
#include <hip/hip_runtime.h>
#include <hip/hip_bf16.h>
#include <hip/hip_cooperative_groups.h>

namespace cg = cooperative_groups;

// WaveNet on MI355X — round 4: cooperative megakernel for the 40 layers
// (grid.sync between layers, no launch overhead) + m97-style LDS-staged
// skip GEMM (global_load_lds dbuf, BK=32).
//
// Layouts (p = original position in [0,8192)):
//   hf0/hf1 : [b][p][c] f32   residual stream (double-buffered)
//   hb0/hb1 : [b][p][c] bf16  shadow of hf (MFMA B-operand)
//   Z       : [b][p4][q] bf16, q = layer*32+o  (K-major rows for skip GEMM)
//   skipb   : [b][p4][s] bf16 (relu applied)
//   wA      : [40][64 out(f,g)][64 k(tap0 c, tap1 c)] bf16
//   wR      : [40][32 c][32 o] bf16
//   wskB    : [512 s][1280 q] bf16  (K-major, same row stride as Z)
//   ewB     : [256 cls][512 s] bf16

#define BATCH   8
#define SEQ     8192
#define RES_CH  32
#define DIL_CH  32
#define SKIP_CH 512
#define CLASSES 256
#define NLAYERS 40
#define OUTLEN  4096
#define PSTART  (SEQ - OUTLEN)      // 4096
#define QTOT    (NLAYERS * DIL_CH)  // 1280

typedef __attribute__((ext_vector_type(8))) short bf16x8;
typedef __attribute__((ext_vector_type(4))) short short4_t;
typedef __attribute__((ext_vector_type(8))) short short8_t;
typedef __attribute__((ext_vector_type(4))) float f32x4;

__device__ __forceinline__ float fast_sigmoid(float x) {
    return __builtin_amdgcn_rcpf(1.0f + __expf(-x));
}
__device__ __forceinline__ float fast_tanh(float x) {
    return 1.0f - 2.0f * __builtin_amdgcn_rcpf(1.0f + __expf(2.0f * x));
}
__device__ __forceinline__ short f2bf(float x) {
    unsigned u = __float_as_uint(x);
    unsigned r = (u + 0x7fffu + ((u >> 16) & 1u)) >> 16;
    return (short)r;
}

#define GLOAD_LDS16(g, l)                                                    \
    __builtin_amdgcn_global_load_lds(                                        \
        (const __attribute__((address_space(1))) unsigned int*)(g),          \
        (__attribute__((address_space(3))) unsigned int*)(l), 16, 0, 0)

// ---------------- cooperative megakernel: prep + 40 layers ----------------
__global__ __launch_bounds__(256) void k_mega(
    const float* __restrict__ x, const float* __restrict__ sw,
    const float* __restrict__ fw, const float* __restrict__ gw,
    const float* __restrict__ rw, const float* __restrict__ wsk,
    const float* __restrict__ ew,
    float* hfA, float* hfB, short* hbA, short* hbB,
    short* Z, short* wA, short* wR, short* wskB, short* ewB)
{
    cg::grid_group grid = cg::this_grid();
    __shared__ short zl[4][32][40];   // per-wave z tile [pos][o], 80B rows

    // ---- phase 0: prep (grid-stride) ----
    {
        const int gt = blockIdx.x * 256 + threadIdx.x;
        const int gn = gridDim.x * 256;
        for (int idx = gt; idx < BATCH * SEQ; idx += gn) {
            float v = x[idx];
            float* hp = hfA + (size_t)idx * RES_CH;
            short* bp = hbA + (size_t)idx * RES_CH;
#pragma unroll
            for (int c = 0; c < RES_CH; ++c) {
                float t = v * sw[c];
                hp[c] = t;
                bp[c] = f2bf(t);
            }
        }
        for (int idx = gt; idx < NLAYERS * 64 * 64; idx += gn) {
            int k = idx & 63, o = (idx >> 6) & 63, i = idx >> 12;
            int tap = k >> 5, c = k & 31;
            float v = (o < 32) ? fw[((i * 32 + o) * 32 + c) * 2 + tap]
                               : gw[((i * 32 + (o - 32)) * 32 + c) * 2 + tap];
            wA[idx] = f2bf(v);
        }
        for (int idx = gt; idx < NLAYERS * 1024; idx += gn)
            wR[idx] = f2bf(rw[idx]);
        for (int idx = gt; idx < SKIP_CH * QTOT; idx += gn) {
            int s = idx / QTOT, q = idx - s * QTOT;
            int i = q >> 5, o = q & 31;
            wskB[idx] = f2bf(wsk[((size_t)i * SKIP_CH + s) * 32 + o]);
        }
        for (int idx = gt; idx < CLASSES * SKIP_CH; idx += gn)
            ewB[idx] = f2bf(ew[idx]);
    }
    grid.sync();

    // ---- phases 1..40: layers ----
    const int lane = threadIdx.x & 63;
    const int w    = threadIdx.x >> 6;
    const int r = lane & 15, g14 = lane >> 4;
    const int gwave = blockIdx.x * 4 + w;
    const int nwv   = gridDim.x * 4;

    float* hfc = hfA; float* hfn = hfB;
    short* hbc = hbA; short* hbn = hbB;
    int pmin = 0;

#pragma unroll 1
    for (int li = 0; li < NLAYERS; ++li) {
        const int d = 1 << (li - (li / 10) * 10);
        const int pmo = pmin + d;
        const int nchunk = (SEQ - pmo + 31) >> 5;   // 32-pos chunks per batch
        const int ntask  = nchunk * BATCH;
        const short* wAl = wA + li * 4096;
        const short* wRl = wR + li * 1024;

#pragma unroll 1
        for (int t = gwave; t < ntask; t += nwv) {
            const int b  = t / nchunk;
            const int ci = t - b * nchunk;
            const int p0 = pmo + ci * 32;

            const short* hbb = hbc + (size_t)b * SEQ * RES_CH;
            const float* hfb = hfc + (size_t)b * SEQ * RES_CH;

            int pl[2]; bool pv[2];
#pragma unroll
            for (int fj = 0; fj < 2; ++fj) {
                int p = p0 + fj * 16 + r;
                pv[fj] = p < SEQ;
                pl[fj] = pv[fj] ? p : SEQ - 1;
            }

            bf16x8 av[4][2];
#pragma unroll
            for (int fi = 0; fi < 4; ++fi)
#pragma unroll
                for (int kt = 0; kt < 2; ++kt)
                    av[fi][kt] = *(const bf16x8*)(wAl + (fi * 16 + r) * 64 + kt * 32 + g14 * 8);

            bf16x8 bv[2][2];
#pragma unroll
            for (int fj = 0; fj < 2; ++fj) {
                bv[fj][0] = *(const bf16x8*)(hbb + (size_t)(pl[fj] - d) * RES_CH + g14 * 8);
                bv[fj][1] = *(const bf16x8*)(hbb + (size_t)pl[fj] * RES_CH + g14 * 8);
            }

            f32x4 acc[4][2];
            const f32x4 zero4 = {0.f, 0.f, 0.f, 0.f};
#pragma unroll
            for (int fi = 0; fi < 4; ++fi)
#pragma unroll
                for (int fj = 0; fj < 2; ++fj) acc[fi][fj] = zero4;

#pragma unroll
            for (int kt = 0; kt < 2; ++kt)
#pragma unroll
                for (int fi = 0; fi < 4; ++fi)
#pragma unroll
                    for (int fj = 0; fj < 2; ++fj)
                        acc[fi][fj] = __builtin_amdgcn_mfma_f32_16x16x32_bf16(
                            av[fi][kt], bv[fj][kt], acc[fi][fj], 0, 0, 0);

            short4_t zb4[2][2];
#pragma unroll
            for (int fp = 0; fp < 2; ++fp)
#pragma unroll
                for (int fj = 0; fj < 2; ++fj) {
                    short4_t v;
#pragma unroll
                    for (int e = 0; e < 4; ++e) {
                        float zf = fast_tanh(acc[fp][fj][e]) *
                                   fast_sigmoid(acc[fp + 2][fj][e]);
                        v[e] = f2bf(zf);
                    }
                    zb4[fp][fj] = v;
                }

#pragma unroll
            for (int fj = 0; fj < 2; ++fj)
                if (pv[fj] && pl[fj] >= PSTART) {
                    short* zp = Z + ((size_t)b * OUTLEN + (pl[fj] - PSTART)) * QTOT
                                  + li * DIL_CH;
#pragma unroll
                    for (int fp = 0; fp < 2; ++fp)
                        *(short4_t*)(zp + fp * 16 + g14 * 4) = zb4[fp][fj];
                }

            // z -> per-wave LDS tile (same-wave write/read: lgkmcnt only)
#pragma unroll
            for (int fj = 0; fj < 2; ++fj)
#pragma unroll
                for (int fp = 0; fp < 2; ++fp)
                    *(short4_t*)&zl[w][fj * 16 + r][fp * 16 + g14 * 4] = zb4[fp][fj];

            bf16x8 avr[2], bvr[2];
#pragma unroll
            for (int fi = 0; fi < 2; ++fi)
                avr[fi] = *(const bf16x8*)(wRl + (fi * 16 + r) * 32 + g14 * 8);
#pragma unroll
            for (int fj = 0; fj < 2; ++fj)
                bvr[fj] = *(const bf16x8*)&zl[w][fj * 16 + r][g14 * 8];

            f32x4 racc[2][2];
#pragma unroll
            for (int fi = 0; fi < 2; ++fi)
#pragma unroll
                for (int fj = 0; fj < 2; ++fj)
                    racc[fi][fj] = *(const f32x4*)(hfb + (size_t)pl[fj] * RES_CH
                                                       + fi * 16 + g14 * 4);
#pragma unroll
            for (int fi = 0; fi < 2; ++fi)
#pragma unroll
                for (int fj = 0; fj < 2; ++fj)
                    racc[fi][fj] = __builtin_amdgcn_mfma_f32_16x16x32_bf16(
                        avr[fi], bvr[fj], racc[fi][fj], 0, 0, 0);

            float* hfo = hfn + (size_t)b * SEQ * RES_CH;
            short* hbo = hbn + (size_t)b * SEQ * RES_CH;
#pragma unroll
            for (int fj = 0; fj < 2; ++fj)
                if (pv[fj]) {
#pragma unroll
                    for (int fi = 0; fi < 2; ++fi) {
                        *(f32x4*)(hfo + (size_t)pl[fj] * RES_CH + fi * 16 + g14 * 4) =
                            racc[fi][fj];
                        short4_t sv;
#pragma unroll
                        for (int e = 0; e < 4; ++e) sv[e] = f2bf(racc[fi][fj][e]);
                        *(short4_t*)(hbo + (size_t)pl[fj] * RES_CH + fi * 16 + g14 * 4) = sv;
                    }
                }
        }

        grid.sync();
        float* tf = hfc; hfc = hfn; hfn = tf;
        short* tb = hbc; hbc = hbn; hbn = tb;
        pmin = pmo;
    }
}

// ---------------- skip GEMM, m97 structure ----------------
// C[s][p] = relu(sum_q wskB[s][q] * Z[b][p][q]) -> bf16 skipb[b][p][s].
// 256 thr = 4 waves (2s x 2p of 64x64), block tile 128x128, BK=32 (40 steps),
// double-buffered LDS staged via global_load_lds width-16 (linear dest).
__global__ __launch_bounds__(256) void k_skip_m97(
    const short* __restrict__ Z, const short* __restrict__ wskB,
    short* __restrict__ skipb)
{
    __shared__ short At[2][128 * 32];   // [row s][32 k] per buffer, 8KB each
    __shared__ short Bt[2][128 * 32];   // [row p][32 k]

    const int bid = blockIdx.x;          // 1024 blocks
    const int b    = bid & 7;            // one batch per XCD (L2 locality)
    const int rest = bid >> 3;           // 0..127
    const int sb   = rest & 3;           // s fastest: s-blocks L2-adjacent
    const int pb   = rest >> 2;          // 0..31
    const int s0   = sb * 128;
    const int p0   = pb * 128;

    const int lane = threadIdx.x & 63;
    const int w    = threadIdx.x >> 6;
    const int r = lane & 15, g14 = lane >> 4;
    const int soff = (w >> 1) * 64;
    const int poff = (w & 1) * 64;

    const short* Ab = wskB + (size_t)s0 * QTOT;
    const short* Bb = Z + ((size_t)b * OUTLEN + p0) * QTOT;

    // staging: wave w covers rows w*32..w*32+31 of both tiles; 2 issues each.
    const int rb = w * 32;
    const int l4 = lane >> 2;       // 0..15 (sub-row)
    const int c4 = lane & 3;        // 16B block within 64B row

#define SK_STAGE(bf, kt)                                                      \
    {                                                                         \
        _Pragma("unroll") for (int j = 0; j < 2; ++j) {                       \
            const short* ga = Ab + (size_t)(rb + j * 16 + l4) * QTOT          \
                                 + (kt) * 32 + c4 * 8;                        \
            GLOAD_LDS16(ga, &At[bf][(rb + j * 16) * 32]);                     \
            const short* gb = Bb + (size_t)(rb + j * 16 + l4) * QTOT          \
                                 + (kt) * 32 + c4 * 8;                        \
            GLOAD_LDS16(gb, &Bt[bf][(rb + j * 16) * 32]);                     \
        }                                                                     \
    }

    f32x4 acc[4][4];
    const f32x4 zero4 = {0.f, 0.f, 0.f, 0.f};
#pragma unroll
    for (int fi = 0; fi < 4; ++fi)
#pragma unroll
        for (int fj = 0; fj < 4; ++fj) acc[fi][fj] = zero4;

    SK_STAGE(0, 0)
    __syncthreads();

    int cur = 0;
#pragma unroll 1
    for (int kt = 0; kt < QTOT / 32; ++kt) {
        if (kt + 1 < QTOT / 32) SK_STAGE(cur ^ 1, kt + 1)

        bf16x8 av[4], bv[4];
#pragma unroll
        for (int fi = 0; fi < 4; ++fi)
            av[fi] = *(const bf16x8*)&At[cur][(soff + fi * 16 + r) * 32 + g14 * 8];
#pragma unroll
        for (int fj = 0; fj < 4; ++fj)
            bv[fj] = *(const bf16x8*)&Bt[cur][(poff + fj * 16 + r) * 32 + g14 * 8];

#pragma unroll
        for (int fi = 0; fi < 4; ++fi)
#pragma unroll
            for (int fj = 0; fj < 4; ++fj)
                acc[fi][fj] = __builtin_amdgcn_mfma_f32_16x16x32_bf16(
                    av[fi], bv[fj], acc[fi][fj], 0, 0, 0);

        __syncthreads();   // drains vmcnt (stage kt+1 done) + reads of cur done
        cur ^= 1;
    }

    short* skb = skipb + (size_t)b * OUTLEN * SKIP_CH;
#pragma unroll
    for (int fj = 0; fj < 4; ++fj) {
        int p = p0 + poff + fj * 16 + r;
#pragma unroll
        for (int fi = 0; fi < 4; ++fi) {
            int s = s0 + soff + fi * 16 + g14 * 4;
            short4_t v;
#pragma unroll
            for (int e = 0; e < 4; ++e) v[e] = f2bf(fmaxf(acc[fi][fj][e], 0.f));
            *(short4_t*)(skb + (size_t)p * SKIP_CH + s) = v;
        }
    }
}

// ---------------- end GEMM (unchanged, passing) ----------------
#define EK_LOAD(A, B, kt)                                                   \
    {                                                                       \
        _Pragma("unroll") for (int fi = 0; fi < 4; ++fi)                    \
            A[fi] = *(const bf16x8*)(ewB + aoff[fi] + (kt) * 32);           \
        _Pragma("unroll") for (int fj = 0; fj < 4; ++fj)                    \
            B[fj] = *(const bf16x8*)(skb + boff[fj] + (kt) * 32);           \
    }
#define EK_MFMA(A, B)                                                       \
    {                                                                       \
        _Pragma("unroll") for (int fi = 0; fi < 4; ++fi)                    \
            _Pragma("unroll") for (int fj = 0; fj < 4; ++fj)                \
                acc[fi][fj] = __builtin_amdgcn_mfma_f32_16x16x32_bf16(      \
                    A[fi], B[fj], acc[fi][fj], 0, 0, 0);                    \
    }

__global__ __launch_bounds__(256) void k_end_mfma(
    const short* __restrict__ skipB, const short* __restrict__ ewB,
    const float* __restrict__ eb, float* __restrict__ out)
{
    const int n = blockIdx.x;            // 512 blocks
    const int b = n & 7;
    const int idx = n >> 3;              // 0..63
    const int cb = idx & 1;
    const int pb = idx >> 1;             // 0..31
    const int lane = threadIdx.x & 63;
    const int w = threadIdx.x >> 6;
    const int c0 = cb * 128 + (w >> 1) * 64;
    const int p0 = pb * 128 + (w & 1) * 64;
    const int r = lane & 15, g = lane >> 4;

    const short* skb = skipB + (size_t)b * OUTLEN * SKIP_CH;

    int aoff[4], boff[4];
#pragma unroll
    for (int fi = 0; fi < 4; ++fi) aoff[fi] = (c0 + fi * 16 + r) * SKIP_CH + g * 8;
#pragma unroll
    for (int fj = 0; fj < 4; ++fj) boff[fj] = (p0 + fj * 16 + r) * SKIP_CH + g * 8;

    f32x4 acc[4][4];
    const f32x4 zero4 = {0.f, 0.f, 0.f, 0.f};
#pragma unroll
    for (int fi = 0; fi < 4; ++fi)
#pragma unroll
        for (int fj = 0; fj < 4; ++fj) acc[fi][fj] = zero4;

    bf16x8 a0[4], b0[4], a1[4], b1[4];
    EK_LOAD(a0, b0, 0)
#pragma unroll 1
    for (int kt = 0; kt + 2 < SKIP_CH / 32; kt += 2) {
        EK_LOAD(a1, b1, kt + 1)
        EK_MFMA(a0, b0)
        EK_LOAD(a0, b0, kt + 2)
        EK_MFMA(a1, b1)
    }
    EK_LOAD(a1, b1, SKIP_CH / 32 - 1)
    EK_MFMA(a0, b0)
    EK_MFMA(a1, b1)

#pragma unroll
    for (int fj = 0; fj < 4; ++fj) {
        int p = p0 + fj * 16 + r;
#pragma unroll
        for (int fi = 0; fi < 4; ++fi) {
            int cls = c0 + fi * 16 + g * 4;
            f32x4 bias = *(const f32x4*)(eb + cls);
            f32x4 v;
#pragma unroll
            for (int e = 0; e < 4; ++e) v[e] = acc[fi][fj][e] + bias[e];
            *(f32x4*)(out + ((size_t)b * OUTLEN + p) * CLASSES + cls) = v;
        }
    }
}

extern "C" void kernel_launch(void* const* d_in, const int* in_sizes, int n_in,
                              void* d_out, int out_size, void* d_ws, size_t ws_size,
                              hipStream_t stream) {
    const float* x   = (const float*)d_in[0];
    const float* sw  = (const float*)d_in[1];
    const float* fw  = (const float*)d_in[2];
    const float* gw  = (const float*)d_in[3];
    const float* rw  = (const float*)d_in[4];
    const float* wsk = (const float*)d_in[5];
    const float* ew  = (const float*)d_in[6];
    const float* eb  = (const float*)d_in[7];
    float* out = (float*)d_out;

    const size_t HN = (size_t)BATCH * SEQ * RES_CH;   // 2097152
    float* hf0 = (float*)d_ws;
    float* hf1 = hf0 + HN;
    short* hb0 = (short*)(hf1 + HN);
    short* hb1 = hb0 + HN;
    short* Z     = hb1 + HN;                              // 8*4096*1280
    short* skipb = Z + (size_t)BATCH * OUTLEN * QTOT;     // 8*4096*512
    short* wA    = skipb + (size_t)BATCH * OUTLEN * SKIP_CH;  // 40*64*64
    short* wR    = wA + NLAYERS * 64 * 64;                // 40*32*32
    short* wskB  = wR + NLAYERS * 32 * 32;                // 512*1280
    short* ewB   = wskB + (size_t)SKIP_CH * QTOT;         // 256*512

    // size cooperative grid by occupancy (grid-stride loops tolerate any size)
    int dev = 0;
    hipGetDevice(&dev);
    int nCU = 256;
    hipDeviceGetAttribute(&nCU, hipDeviceAttributeMultiprocessorCount, dev);
    int maxB = 0;
    hipOccupancyMaxActiveBlocksPerMultiprocessor(&maxB, k_mega, 256, 0);
    if (maxB < 1) maxB = 1;
    long long gl = (long long)nCU * maxB;
    int grid = (int)(gl > 1024 ? 1024 : gl);

    void* kargs[] = {
        (void*)&x, (void*)&sw, (void*)&fw, (void*)&gw, (void*)&rw,
        (void*)&wsk, (void*)&ew,
        (void*)&hf0, (void*)&hf1, (void*)&hb0, (void*)&hb1,
        (void*)&Z, (void*)&wA, (void*)&wR, (void*)&wskB, (void*)&ewB,
    };
    hipLaunchCooperativeKernel((void*)k_mega, dim3(grid), dim3(256), kargs, 0, stream);

    k_skip_m97<<<dim3(1024), 256, 0, stream>>>(Z, wskB, skipb);
    k_end_mfma<<<dim3(512), 256, 0, stream>>>(skipb, ewB, eb, out);
}

// Round 5
// 382.989 us; speedup vs baseline: 7.7097x; 7.7097x over previous
//
#include <hip/hip_runtime.h>
#include <hip/hip_bf16.h>

// WaveNet on MI355X — round 5: fused layer groups (register-carried f32
// residual + LDS-tiled bf16 taps with halo recompute), 8 launches for 40
// layers. Skip/end GEMMs unchanged from round 4 (passing).
//
// Layouts (p = original position in [0,8192)):
//   hf0/hf1 : [b][p][c] f32   residual stream (double-buffered per group)
//   hb0/hb1 : [b][p][c] bf16  shadow of hf (MFMA B-operand / taps)
//   Z       : [b][p4][q] bf16, q = layer*32+o  (K-major rows for skip GEMM)
//   skipb   : [b][p4][s] bf16 (relu applied)
//   wA      : [40][64 out(f,g)][64 k(tap0 c, tap1 c)] bf16
//   wR      : [40][32 c][32 o] bf16
//   wskB    : [512 s][1280 q] bf16
//   ewB     : [256 cls][512 s] bf16

#define BATCH   8
#define SEQ     8192
#define RES_CH  32
#define DIL_CH  32
#define SKIP_CH 512
#define CLASSES 256
#define NLAYERS 40
#define OUTLEN  4096
#define PSTART  (SEQ - OUTLEN)      // 4096
#define QTOT    (NLAYERS * DIL_CH)  // 1280

typedef __attribute__((ext_vector_type(8))) short bf16x8;
typedef __attribute__((ext_vector_type(4))) short short4_t;
typedef __attribute__((ext_vector_type(4))) float f32x4;

__device__ __forceinline__ float fast_sigmoid(float x) {
    return __builtin_amdgcn_rcpf(1.0f + __expf(-x));
}
__device__ __forceinline__ float fast_tanh(float x) {
    return 1.0f - 2.0f * __builtin_amdgcn_rcpf(1.0f + __expf(2.0f * x));
}
__device__ __forceinline__ short f2bf(float x) {
    unsigned u = __float_as_uint(x);
    unsigned r = (u + 0x7fffu + ((u >> 16) & 1u)) >> 16;
    return (short)r;
}
__device__ __forceinline__ float bf2f(short s) {
    return __uint_as_float(((unsigned)(unsigned short)s) << 16);
}
// LDS tile byte-offset with XOR swizzle (rows of 64B = 32 bf16 channels).
// XOR bits 4..5 of the column byte with row bits 0..2 -> 2-way max on
// ds_read_b128 column-slice reads (free per m136).
__device__ __forceinline__ int tswz(int row, int cb) {
    return row * 64 + (cb ^ (((row & 3) << 4) | ((row & 4) << 3)));
}

#define GLOAD_LDS16(g, l)                                                    \
    __builtin_amdgcn_global_load_lds(                                        \
        (const __attribute__((address_space(1))) unsigned int*)(g),          \
        (__attribute__((address_space(3))) unsigned int*)(l), 16, 0, 0)

// ---------------- prep: h init + all weight reshapes (one launch) ----------
__global__ __launch_bounds__(256) void k_prep(
    const float* __restrict__ x, const float* __restrict__ sw,
    const float* __restrict__ fw, const float* __restrict__ gw,
    const float* __restrict__ rw, const float* __restrict__ wsk,
    const float* __restrict__ ew,
    float* __restrict__ hf, short* __restrict__ hb,
    short* __restrict__ wA, short* __restrict__ wR,
    short* __restrict__ wskB, short* __restrict__ ewB)
{
    const int gt = blockIdx.x * 256 + threadIdx.x;
    const int gn = gridDim.x * 256;
    for (int idx = gt; idx < BATCH * SEQ; idx += gn) {
        float v = x[idx];
        float* hp = hf + (size_t)idx * RES_CH;
        short* bp = hb + (size_t)idx * RES_CH;
#pragma unroll
        for (int c = 0; c < RES_CH; ++c) {
            float t = v * sw[c];
            hp[c] = t;
            bp[c] = f2bf(t);
        }
    }
    for (int idx = gt; idx < NLAYERS * 64 * 64; idx += gn) {
        int k = idx & 63, o = (idx >> 6) & 63, i = idx >> 12;
        int tap = k >> 5, c = k & 31;
        float v = (o < 32) ? fw[((i * 32 + o) * 32 + c) * 2 + tap]
                           : gw[((i * 32 + (o - 32)) * 32 + c) * 2 + tap];
        wA[idx] = f2bf(v);
    }
    for (int idx = gt; idx < NLAYERS * 1024; idx += gn)
        wR[idx] = f2bf(rw[idx]);
    for (int idx = gt; idx < SKIP_CH * QTOT; idx += gn) {
        int s = idx / QTOT, q = idx - s * QTOT;
        int i = q >> 5, o = q & 31;
        wskB[idx] = f2bf(wsk[((size_t)i * SKIP_CH + s) * 32 + o]);
    }
    for (int idx = gt; idx < CLASSES * SKIP_CH; idx += gn)
        ewB[idx] = f2bf(ew[idx]);
}

// ---------------- fused layer-group kernel ----------------
// One chunk = 32 positions processed by one wave through one layer.
template<bool OWNED>
__device__ __forceinline__ void chunk_body(
    int cp0, bool bglob, bool last, int d, int tog,
    const short* __restrict__ hbb, const float* __restrict__ hfb,
    float* __restrict__ hfo, short* __restrict__ hbo,
    short* __restrict__ zbb, int liq,
    const char* trd, char* tw,
    const bf16x8 (&av)[4][2], const bf16x8 (&avr)[2],
    short (*zlw)[40], f32x4 (*carryc)[2][2],
    int r, int g14)
{
    int pl[2]; bool pv[2];
#pragma unroll
    for (int fj = 0; fj < 2; ++fj) {
        int p = cp0 + fj * 16 + r;
        pv[fj] = p < SEQ;
        pl[fj] = pv[fj] ? p : SEQ - 1;
    }

    // B fragments: kt=0 tap(p-d), kt=1 tap(p)
    bf16x8 bv[2][2];
    if (bglob) {
#pragma unroll
        for (int fj = 0; fj < 2; ++fj) {
            bv[fj][0] = *(const bf16x8*)(hbb + (pl[fj] - d) * 32 + g14 * 8);
            bv[fj][1] = *(const bf16x8*)(hbb + pl[fj] * 32 + g14 * 8);
        }
    } else {
#pragma unroll
        for (int fj = 0; fj < 2; ++fj) {
            int tr = pl[fj] - tog;
            bv[fj][0] = *(const bf16x8*)(trd + tswz(tr - d, g14 * 16));
            bv[fj][1] = *(const bf16x8*)(trd + tswz(tr, g14 * 16));
        }
    }

    const f32x4 zero4 = {0.f, 0.f, 0.f, 0.f};
    f32x4 acc[4][2];
#pragma unroll
    for (int fi = 0; fi < 4; ++fi)
#pragma unroll
        for (int fj = 0; fj < 2; ++fj) acc[fi][fj] = zero4;
#pragma unroll
    for (int kt = 0; kt < 2; ++kt)
#pragma unroll
        for (int fi = 0; fi < 4; ++fi)
#pragma unroll
            for (int fj = 0; fj < 2; ++fj)
                acc[fi][fj] = __builtin_amdgcn_mfma_f32_16x16x32_bf16(
                    av[fi][kt], bv[fj][kt], acc[fi][fj], 0, 0, 0);

    // z = tanh(f)*sigmoid(g), lane-local (f rows fi, g rows fi+2)
    short4_t zb4[2][2];
#pragma unroll
    for (int fp = 0; fp < 2; ++fp)
#pragma unroll
        for (int fj = 0; fj < 2; ++fj) {
            short4_t v;
#pragma unroll
            for (int e = 0; e < 4; ++e)
                v[e] = f2bf(fast_tanh(acc[fp][fj][e]) *
                            fast_sigmoid(acc[fp + 2][fj][e]));
            zb4[fp][fj] = v;
        }

    if constexpr (OWNED) {
#pragma unroll
        for (int fj = 0; fj < 2; ++fj)
            if (pv[fj] && pl[fj] >= PSTART) {
                short* zp = zbb + (size_t)(pl[fj] - PSTART) * QTOT + liq;
                *(short4_t*)(zp + g14 * 4) = zb4[0][fj];
                *(short4_t*)(zp + 16 + g14 * 4) = zb4[1][fj];
            }
    }

    // z -> per-wave LDS tile for res-GEMM B-operand (same-wave, no barrier)
#pragma unroll
    for (int fj = 0; fj < 2; ++fj)
#pragma unroll
        for (int fp = 0; fp < 2; ++fp)
            *(short4_t*)&zlw[fj * 16 + r][fp * 16 + g14 * 4] = zb4[fp][fj];
    bf16x8 bvr[2];
#pragma unroll
    for (int fj = 0; fj < 2; ++fj)
        bvr[fj] = *(const bf16x8*)&zlw[fj * 16 + r][g14 * 8];

    // C-in for the res GEMM
    f32x4 racc[2][2];
    if constexpr (OWNED) {
        if (bglob) {
#pragma unroll
            for (int fi = 0; fi < 2; ++fi)
#pragma unroll
                for (int fj = 0; fj < 2; ++fj)
                    racc[fi][fj] = *(const f32x4*)(hfb + pl[fj] * 32 + fi * 16 + g14 * 4);
        } else {
#pragma unroll
            for (int fi = 0; fi < 2; ++fi)
#pragma unroll
                for (int fj = 0; fj < 2; ++fj)
                    racc[fi][fj] = (*carryc)[fi][fj];
        }
    } else {
#pragma unroll
        for (int fj = 0; fj < 2; ++fj)
#pragma unroll
            for (int fi = 0; fi < 2; ++fi) {
                short4_t hv;
                if (bglob)
                    hv = *(const short4_t*)(hbb + pl[fj] * 32 + fi * 16 + g14 * 4);
                else
                    hv = *(const short4_t*)(trd + tswz(pl[fj] - tog, fi * 32 + g14 * 8));
                f32x4 cv;
#pragma unroll
                for (int e = 0; e < 4; ++e) cv[e] = bf2f(hv[e]);
                racc[fi][fj] = cv;
            }
    }

#pragma unroll
    for (int fi = 0; fi < 2; ++fi)
#pragma unroll
        for (int fj = 0; fj < 2; ++fj)
            racc[fi][fj] = __builtin_amdgcn_mfma_f32_16x16x32_bf16(
                avr[fi], bvr[fj], racc[fi][fj], 0, 0, 0);

    if constexpr (OWNED) {
#pragma unroll
        for (int fi = 0; fi < 2; ++fi)
#pragma unroll
            for (int fj = 0; fj < 2; ++fj)
                (*carryc)[fi][fj] = racc[fi][fj];
    }

    if (!last) {
        // store h_out tile (bf16) for next layer's taps / halo C-in
#pragma unroll
        for (int fj = 0; fj < 2; ++fj)
            if (pv[fj]) {
                int tr = pl[fj] - tog;
#pragma unroll
                for (int fi = 0; fi < 2; ++fi) {
                    short4_t sv;
#pragma unroll
                    for (int e = 0; e < 4; ++e) sv[e] = f2bf(racc[fi][fj][e]);
                    *(short4_t*)(tw + tswz(tr, fi * 32 + g14 * 8)) = sv;
                }
            }
    } else {
        if constexpr (OWNED) {
#pragma unroll
            for (int fj = 0; fj < 2; ++fj)
                if (pv[fj]) {
#pragma unroll
                    for (int fi = 0; fi < 2; ++fi) {
                        *(f32x4*)(hfo + pl[fj] * 32 + fi * 16 + g14 * 4) = racc[fi][fj];
                        short4_t sv;
#pragma unroll
                        for (int e = 0; e < 4; ++e) sv[e] = f2bf(racc[fi][fj][e]);
                        *(short4_t*)(hbo + pl[fj] * 32 + fi * 16 + g14 * 4) = sv;
                    }
                }
        }
    }
}

// LC layers fused; S owned positions/block; TH halo rows (mult of 32,
// >= max over t of nh_t*32 + d_t); NTB tile buffers (2 if LC>2 else 1).
template<int LC, int S, int TH, int NTB>
__global__ __launch_bounds__(256, 2) void k_fused(
    const float* __restrict__ hfin, const short* __restrict__ hbin,
    float* __restrict__ hfout, short* __restrict__ hbout,
    const short* __restrict__ wAg, const short* __restrict__ wRg,
    short* __restrict__ Z, int li0, int pminIn, int hsum, int segbase)
{
    constexpr int TROWS = TH + S;
    constexpr int OPW = S / 128;          // owned chunks per wave
    __shared__ short tile[NTB][TROWS][32];
    __shared__ short zl[4][32][40];

    const int lane = threadIdx.x & 63;
    const int w    = threadIdx.x >> 6;
    const int r = lane & 15, g14 = lane >> 4;
    const int b = blockIdx.y;
    const int seg0 = segbase + blockIdx.x * S;
    const int tog  = seg0 - TH;

    const float* hfb = hfin + (size_t)b * SEQ * RES_CH;
    const short* hbb = hbin + (size_t)b * SEQ * RES_CH;
    float* hfo = hfout + (size_t)b * SEQ * RES_CH;
    short* hbo = hbout + (size_t)b * SEQ * RES_CH;
    short* zbb = Z + (size_t)b * OUTLEN * QTOT;

    f32x4 carry[OPW][2][2];
    int Ht = hsum, pmt = pminIn;

#pragma unroll 1
    for (int t = 0; t < LC; ++t) {
        const int d = 1 << ((li0 + t) % 10);
        Ht -= d; pmt += d;
        const bool bglob = (t == 0);
        const bool last  = (t == LC - 1);
        const short* wAl = wAg + (li0 + t) * 4096;
        const short* wRl = wRg + (li0 + t) * 1024;
        const int liq = (li0 + t) * DIL_CH;
        char* tw = (char*)&tile[t & (NTB - 1)][0][0];
        const char* trd = (const char*)&tile[(t + NTB - 1) & (NTB - 1)][0][0];

        bf16x8 av[4][2];
#pragma unroll
        for (int fi = 0; fi < 4; ++fi)
#pragma unroll
            for (int kt = 0; kt < 2; ++kt)
                av[fi][kt] = *(const bf16x8*)(wAl + (fi * 16 + r) * 64 + kt * 32 + g14 * 8);
        bf16x8 avr[2];
#pragma unroll
        for (int fi = 0; fi < 2; ++fi)
            avr[fi] = *(const bf16x8*)(wRl + (fi * 16 + r) * 32 + g14 * 8);

        // owned chunks: carry stays in registers (static oc indexing)
#pragma unroll
        for (int oc = 0; oc < OPW; ++oc) {
            const int cp0 = seg0 + (oc * 4 + w) * 32;
            chunk_body<true>(cp0, bglob, last, d, tog, hbb, hfb, hfo, hbo,
                             zbb, liq, trd, tw, av, avr, zl[w], &carry[oc],
                             r, g14);
        }
        // halo chunks (left of seg0): recompute, tile-only
        int lo = seg0 - Ht; if (lo < pmt) lo = pmt;
        const int nh = (seg0 - lo + 31) >> 5;
#pragma unroll 1
        for (int hc = w; hc < nh; hc += 4) {
            const int cp0 = seg0 - (hc + 1) * 32;
            chunk_body<false>(cp0, bglob, last, d, tog, hbb, hfb, hfo, hbo,
                              zbb, liq, trd, tw, av, avr, zl[w], nullptr,
                              r, g14);
        }
        __syncthreads();
    }
}

// ---------------- skip GEMM, m97 structure (verbatim round 4) --------------
__global__ __launch_bounds__(256) void k_skip_m97(
    const short* __restrict__ Z, const short* __restrict__ wskB,
    short* __restrict__ skipb)
{
    __shared__ short At[2][128 * 32];
    __shared__ short Bt[2][128 * 32];

    const int bid = blockIdx.x;          // 1024 blocks
    const int b    = bid & 7;            // one batch per XCD
    const int rest = bid >> 3;
    const int sb   = rest & 3;
    const int pb   = rest >> 2;
    const int s0   = sb * 128;
    const int p0   = pb * 128;

    const int lane = threadIdx.x & 63;
    const int w    = threadIdx.x >> 6;
    const int r = lane & 15, g14 = lane >> 4;
    const int soff = (w >> 1) * 64;
    const int poff = (w & 1) * 64;

    const short* Ab = wskB + (size_t)s0 * QTOT;
    const short* Bb = Z + ((size_t)b * OUTLEN + p0) * QTOT;

    const int rb = w * 32;
    const int l4 = lane >> 2;
    const int c4 = lane & 3;

#define SK_STAGE(bf, kt)                                                      \
    {                                                                         \
        _Pragma("unroll") for (int j = 0; j < 2; ++j) {                       \
            const short* ga = Ab + (size_t)(rb + j * 16 + l4) * QTOT          \
                                 + (kt) * 32 + c4 * 8;                        \
            GLOAD_LDS16(ga, &At[bf][(rb + j * 16) * 32]);                     \
            const short* gb = Bb + (size_t)(rb + j * 16 + l4) * QTOT          \
                                 + (kt) * 32 + c4 * 8;                        \
            GLOAD_LDS16(gb, &Bt[bf][(rb + j * 16) * 32]);                     \
        }                                                                     \
    }

    f32x4 acc[4][4];
    const f32x4 zero4 = {0.f, 0.f, 0.f, 0.f};
#pragma unroll
    for (int fi = 0; fi < 4; ++fi)
#pragma unroll
        for (int fj = 0; fj < 4; ++fj) acc[fi][fj] = zero4;

    SK_STAGE(0, 0)
    __syncthreads();

    int cur = 0;
#pragma unroll 1
    for (int kt = 0; kt < QTOT / 32; ++kt) {
        if (kt + 1 < QTOT / 32) SK_STAGE(cur ^ 1, kt + 1)

        bf16x8 av[4], bv[4];
#pragma unroll
        for (int fi = 0; fi < 4; ++fi)
            av[fi] = *(const bf16x8*)&At[cur][(soff + fi * 16 + r) * 32 + g14 * 8];
#pragma unroll
        for (int fj = 0; fj < 4; ++fj)
            bv[fj] = *(const bf16x8*)&Bt[cur][(poff + fj * 16 + r) * 32 + g14 * 8];

#pragma unroll
        for (int fi = 0; fi < 4; ++fi)
#pragma unroll
            for (int fj = 0; fj < 4; ++fj)
                acc[fi][fj] = __builtin_amdgcn_mfma_f32_16x16x32_bf16(
                    av[fi], bv[fj], acc[fi][fj], 0, 0, 0);

        __syncthreads();
        cur ^= 1;
    }

    short* skb = skipb + (size_t)b * OUTLEN * SKIP_CH;
#pragma unroll
    for (int fj = 0; fj < 4; ++fj) {
        int p = p0 + poff + fj * 16 + r;
#pragma unroll
        for (int fi = 0; fi < 4; ++fi) {
            int s = s0 + soff + fi * 16 + g14 * 4;
            short4_t v;
#pragma unroll
            for (int e = 0; e < 4; ++e) v[e] = f2bf(fmaxf(acc[fi][fj][e], 0.f));
            *(short4_t*)(skb + (size_t)p * SKIP_CH + s) = v;
        }
    }
}

// ---------------- end GEMM (verbatim, passing) ----------------
#define EK_LOAD(A, B, kt)                                                   \
    {                                                                       \
        _Pragma("unroll") for (int fi = 0; fi < 4; ++fi)                    \
            A[fi] = *(const bf16x8*)(ewB + aoff[fi] + (kt) * 32);           \
        _Pragma("unroll") for (int fj = 0; fj < 4; ++fj)                    \
            B[fj] = *(const bf16x8*)(skb + boff[fj] + (kt) * 32);           \
    }
#define EK_MFMA(A, B)                                                       \
    {                                                                       \
        _Pragma("unroll") for (int fi = 0; fi < 4; ++fi)                    \
            _Pragma("unroll") for (int fj = 0; fj < 4; ++fj)                \
                acc[fi][fj] = __builtin_amdgcn_mfma_f32_16x16x32_bf16(      \
                    A[fi], B[fj], acc[fi][fj], 0, 0, 0);                    \
    }

__global__ __launch_bounds__(256) void k_end_mfma(
    const short* __restrict__ skipB, const short* __restrict__ ewB,
    const float* __restrict__ eb, float* __restrict__ out)
{
    const int n = blockIdx.x;            // 512 blocks
    const int b = n & 7;
    const int idx = n >> 3;
    const int cb = idx & 1;
    const int pb = idx >> 1;
    const int lane = threadIdx.x & 63;
    const int w = threadIdx.x >> 6;
    const int c0 = cb * 128 + (w >> 1) * 64;
    const int p0 = pb * 128 + (w & 1) * 64;
    const int r = lane & 15, g = lane >> 4;

    const short* skb = skipB + (size_t)b * OUTLEN * SKIP_CH;

    int aoff[4], boff[4];
#pragma unroll
    for (int fi = 0; fi < 4; ++fi) aoff[fi] = (c0 + fi * 16 + r) * SKIP_CH + g * 8;
#pragma unroll
    for (int fj = 0; fj < 4; ++fj) boff[fj] = (p0 + fj * 16 + r) * SKIP_CH + g * 8;

    f32x4 acc[4][4];
    const f32x4 zero4 = {0.f, 0.f, 0.f, 0.f};
#pragma unroll
    for (int fi = 0; fi < 4; ++fi)
#pragma unroll
        for (int fj = 0; fj < 4; ++fj) acc[fi][fj] = zero4;

    bf16x8 a0[4], b0[4], a1[4], b1[4];
    EK_LOAD(a0, b0, 0)
#pragma unroll 1
    for (int kt = 0; kt + 2 < SKIP_CH / 32; kt += 2) {
        EK_LOAD(a1, b1, kt + 1)
        EK_MFMA(a0, b0)
        EK_LOAD(a0, b0, kt + 2)
        EK_MFMA(a1, b1)
    }
    EK_LOAD(a1, b1, SKIP_CH / 32 - 1)
    EK_MFMA(a0, b0)
    EK_MFMA(a1, b1)

#pragma unroll
    for (int fj = 0; fj < 4; ++fj) {
        int p = p0 + fj * 16 + r;
#pragma unroll
        for (int fi = 0; fi < 4; ++fi) {
            int cls = c0 + fi * 16 + g * 4;
            f32x4 bias = *(const f32x4*)(eb + cls);
            f32x4 v;
#pragma unroll
            for (int e = 0; e < 4; ++e) v[e] = acc[fi][fj][e] + bias[e];
            *(f32x4*)(out + ((size_t)b * OUTLEN + p) * CLASSES + cls) = v;
        }
    }
}

extern "C" void kernel_launch(void* const* d_in, const int* in_sizes, int n_in,
                              void* d_out, int out_size, void* d_ws, size_t ws_size,
                              hipStream_t stream) {
    const float* x   = (const float*)d_in[0];
    const float* sw  = (const float*)d_in[1];
    const float* fw  = (const float*)d_in[2];
    const float* gw  = (const float*)d_in[3];
    const float* rw  = (const float*)d_in[4];
    const float* wsk = (const float*)d_in[5];
    const float* ew  = (const float*)d_in[6];
    const float* eb  = (const float*)d_in[7];
    float* out = (float*)d_out;

    const size_t HN = (size_t)BATCH * SEQ * RES_CH;   // 2097152
    float* hf0 = (float*)d_ws;
    float* hf1 = hf0 + HN;
    short* hb0 = (short*)(hf1 + HN);
    short* hb1 = hb0 + HN;
    short* Z     = hb1 + HN;
    short* skipb = Z + (size_t)BATCH * OUTLEN * QTOT;
    short* wA    = skipb + (size_t)BATCH * OUTLEN * SKIP_CH;
    short* wR    = wA + NLAYERS * 64 * 64;
    short* wskB  = wR + NLAYERS * 32 * 32;
    short* ewB   = wskB + (size_t)SKIP_CH * QTOT;

    k_prep<<<dim3(1024), 256, 0, stream>>>(x, sw, fw, gw, rw, wsk, ew,
                                           hf0, hb0, wA, wR, wskB, ewB);

    float* hf[2] = {hf0, hf1};
    short* hb[2] = {hb0, hb1};
    int cur = 0, pmin = 0;
    for (int dec = 0; dec < 4; ++dec) {
        int li0 = dec * 10;
        // group 1: d = 1..128 (8 layers), halo sum 255
        int segbase = pmin + 255;
        int nseg = (SEQ - segbase + 255) / 256;
        k_fused<8, 256, 288, 2><<<dim3(nseg, BATCH), 256, 0, stream>>>(
            hf[cur], hb[cur], hf[cur ^ 1], hb[cur ^ 1], wA, wR, Z,
            li0, pmin, 255, segbase);
        cur ^= 1; pmin = segbase;
        // group 2: d = 256, 512 (2 layers), halo sum 768
        segbase = pmin + 768;
        nseg = (SEQ - segbase + 255) / 256;
        k_fused<2, 256, 512, 1><<<dim3(nseg, BATCH), 256, 0, stream>>>(
            hf[cur], hb[cur], hf[cur ^ 1], hb[cur ^ 1], wA, wR, Z,
            li0 + 8, pmin, 768, segbase);
        cur ^= 1; pmin = segbase;
    }

    k_skip_m97<<<dim3(1024), 256, 0, stream>>>(Z, wskB, skipb);
    k_end_mfma<<<dim3(512), 256, 0, stream>>>(skipb, ewB, eb, out);
}

// Round 6
// 354.673 us; speedup vs baseline: 8.3252x; 1.0798x over previous
//
#include <hip/hip_runtime.h>
#include <hip/hip_bf16.h>

// WaveNet on MI355X — round 6:
//  (1) wA row-permutation makes the activated z register vector directly
//      usable as the res-GEMM B-fragment AND the Z store -> no LDS z
//      round-trip in the fused layer kernel.
//  (2) k_skip/k_end: m97 LDS-staged GEMM with 16B-block XOR swizzle
//      (swizzled global source + swizzled ds_read; LDS linear).
//
// Layouts (p = original position in [0,8192)):
//   hf0/hf1 : [b][p][c] f32   residual stream (double-buffered per group)
//   hb0/hb1 : [b][p][c] bf16  shadow of hf (MFMA B-operand / taps)
//   Z       : [b][p4][q] bf16, q = layer*32+o
//   skipb   : [b][p4][s] bf16 (relu applied)
//   wA      : [40][64 rows][64 k] bf16, row rho = fp*16+g*4+e (+32 for gate)
//             holds conv output o = g*8+fp*4+e  (D-frag == B-frag trick)
//   wR      : [40][32 c][32 o] bf16
//   wskB    : [512 s][1280 q] bf16
//   ewB     : [256 cls][512 s] bf16

#define BATCH   8
#define SEQ     8192
#define RES_CH  32
#define DIL_CH  32
#define SKIP_CH 512
#define CLASSES 256
#define NLAYERS 40
#define OUTLEN  4096
#define PSTART  (SEQ - OUTLEN)      // 4096
#define QTOT    (NLAYERS * DIL_CH)  // 1280

typedef __attribute__((ext_vector_type(8))) short bf16x8;
typedef __attribute__((ext_vector_type(4))) short short4_t;
typedef __attribute__((ext_vector_type(4))) float f32x4;

__device__ __forceinline__ float fast_sigmoid(float x) {
    return __builtin_amdgcn_rcpf(1.0f + __expf(-x));
}
__device__ __forceinline__ float fast_tanh(float x) {
    return 1.0f - 2.0f * __builtin_amdgcn_rcpf(1.0f + __expf(2.0f * x));
}
__device__ __forceinline__ short f2bf(float x) {
    unsigned u = __float_as_uint(x);
    unsigned r = (u + 0x7fffu + ((u >> 16) & 1u)) >> 16;
    return (short)r;
}
__device__ __forceinline__ float bf2f(short s) {
    return __uint_as_float(((unsigned)(unsigned short)s) << 16);
}
// layer-tile byte-offset swizzle (rows of 64B)
__device__ __forceinline__ int tswz(int row, int cb) {
    return row * 64 + (cb ^ (((row & 3) << 4) | ((row & 4) << 3)));
}

#define GLOAD_LDS16(g, l)                                                    \
    __builtin_amdgcn_global_load_lds(                                        \
        (const __attribute__((address_space(1))) unsigned int*)(g),          \
        (__attribute__((address_space(3))) unsigned int*)(l), 16, 0, 0)

// ---------------- prep ----------------
__global__ __launch_bounds__(256) void k_prep(
    const float* __restrict__ x, const float* __restrict__ sw,
    const float* __restrict__ fw, const float* __restrict__ gw,
    const float* __restrict__ rw, const float* __restrict__ wsk,
    const float* __restrict__ ew,
    float* __restrict__ hf, short* __restrict__ hb,
    short* __restrict__ wA, short* __restrict__ wR,
    short* __restrict__ wskB, short* __restrict__ ewB)
{
    const int gt = blockIdx.x * 256 + threadIdx.x;
    const int gn = gridDim.x * 256;
    for (int idx = gt; idx < BATCH * SEQ; idx += gn) {
        float v = x[idx];
        float* hp = hf + (size_t)idx * RES_CH;
        short* bp = hb + (size_t)idx * RES_CH;
#pragma unroll
        for (int c = 0; c < RES_CH; ++c) {
            float t = v * sw[c];
            hp[c] = t;
            bp[c] = f2bf(t);
        }
    }
    // wA with the permuted row order: row rho (within [0,32)) holds output
    // o = g*8 + fp*4 + e where rho = fp*16 + g*4 + e; rows [32,64) = gate.
    for (int idx = gt; idx < NLAYERS * 64 * 64; idx += gn) {
        int k = idx & 63, rho = (idx >> 6) & 63, i = idx >> 12;
        int tap = k >> 5, c = k & 31;
        int fgsel = rho >> 5, rr = rho & 31;
        int fp = rr >> 4, gg = (rr >> 2) & 3, e = rr & 3;
        int o = gg * 8 + fp * 4 + e;
        float v = fgsel ? gw[((i * 32 + o) * 32 + c) * 2 + tap]
                        : fw[((i * 32 + o) * 32 + c) * 2 + tap];
        wA[idx] = f2bf(v);
    }
    for (int idx = gt; idx < NLAYERS * 1024; idx += gn)
        wR[idx] = f2bf(rw[idx]);
    for (int idx = gt; idx < SKIP_CH * QTOT; idx += gn) {
        int s = idx / QTOT, q = idx - s * QTOT;
        int i = q >> 5, o = q & 31;
        wskB[idx] = f2bf(wsk[((size_t)i * SKIP_CH + s) * 32 + o]);
    }
    for (int idx = gt; idx < CLASSES * SKIP_CH; idx += gn)
        ewB[idx] = f2bf(ew[idx]);
}

// ---------------- fused layer-group kernel ----------------
template<bool OWNED>
__device__ __forceinline__ void chunk_body(
    int cp0, bool bglob, bool last, int d, int tog,
    const short* __restrict__ hbb, const float* __restrict__ hfb,
    float* __restrict__ hfo, short* __restrict__ hbo,
    short* __restrict__ zbb, int liq,
    const char* trd, char* tw,
    const bf16x8 (&av)[4][2], const bf16x8 (&avr)[2],
    f32x4 (*carryc)[2][2],
    int r, int g14)
{
    int pl[2]; bool pv[2];
#pragma unroll
    for (int fj = 0; fj < 2; ++fj) {
        int p = cp0 + fj * 16 + r;
        pv[fj] = p < SEQ;
        pl[fj] = pv[fj] ? p : SEQ - 1;
    }

    // B fragments: kt=0 tap(p-d), kt=1 tap(p)
    bf16x8 bv[2][2];
    if (bglob) {
#pragma unroll
        for (int fj = 0; fj < 2; ++fj) {
            bv[fj][0] = *(const bf16x8*)(hbb + (pl[fj] - d) * 32 + g14 * 8);
            bv[fj][1] = *(const bf16x8*)(hbb + pl[fj] * 32 + g14 * 8);
        }
    } else {
#pragma unroll
        for (int fj = 0; fj < 2; ++fj) {
            int tr = pl[fj] - tog;
            bv[fj][0] = *(const bf16x8*)(trd + tswz(tr - d, g14 * 16));
            bv[fj][1] = *(const bf16x8*)(trd + tswz(tr, g14 * 16));
        }
    }

    const f32x4 zero4 = {0.f, 0.f, 0.f, 0.f};
    f32x4 acc[4][2];
#pragma unroll
    for (int fi = 0; fi < 4; ++fi)
#pragma unroll
        for (int fj = 0; fj < 2; ++fj) acc[fi][fj] = zero4;
#pragma unroll
    for (int kt = 0; kt < 2; ++kt)
#pragma unroll
        for (int fi = 0; fi < 4; ++fi)
#pragma unroll
            for (int fj = 0; fj < 2; ++fj)
                acc[fi][fj] = __builtin_amdgcn_mfma_f32_16x16x32_bf16(
                    av[fi][kt], bv[fj][kt], acc[fi][fj], 0, 0, 0);

    // z = tanh(f)*sigmoid(g). With the permuted wA, lane (r,g) reg (fp,e)
    // holds output o = g*8+fp*4+e at p = cp0+fj*16+r -> zv8[fj] is directly
    // the res-GEMM B-fragment (k = o = g*8+j) AND the 16B Z-store vector.
    bf16x8 zv8[2];
#pragma unroll
    for (int fj = 0; fj < 2; ++fj)
#pragma unroll
        for (int fp = 0; fp < 2; ++fp)
#pragma unroll
            for (int e = 0; e < 4; ++e)
                zv8[fj][fp * 4 + e] =
                    f2bf(fast_tanh(acc[fp][fj][e]) *
                         fast_sigmoid(acc[fp + 2][fj][e]));

    if constexpr (OWNED) {
#pragma unroll
        for (int fj = 0; fj < 2; ++fj)
            if (pv[fj] && pl[fj] >= PSTART) {
                short* zp = zbb + (size_t)(pl[fj] - PSTART) * QTOT + liq;
                *(bf16x8*)(zp + g14 * 8) = zv8[fj];
            }
    }

    // res GEMM C-in
    f32x4 racc[2][2];
    if constexpr (OWNED) {
        if (bglob) {
#pragma unroll
            for (int fi = 0; fi < 2; ++fi)
#pragma unroll
                for (int fj = 0; fj < 2; ++fj)
                    racc[fi][fj] = *(const f32x4*)(hfb + pl[fj] * 32 + fi * 16 + g14 * 4);
        } else {
#pragma unroll
            for (int fi = 0; fi < 2; ++fi)
#pragma unroll
                for (int fj = 0; fj < 2; ++fj)
                    racc[fi][fj] = (*carryc)[fi][fj];
        }
    } else {
#pragma unroll
        for (int fj = 0; fj < 2; ++fj)
#pragma unroll
            for (int fi = 0; fi < 2; ++fi) {
                short4_t hv;
                if (bglob)
                    hv = *(const short4_t*)(hbb + pl[fj] * 32 + fi * 16 + g14 * 4);
                else
                    hv = *(const short4_t*)(trd + tswz(pl[fj] - tog, fi * 32 + g14 * 8));
                f32x4 cv;
#pragma unroll
                for (int e = 0; e < 4; ++e) cv[e] = bf2f(hv[e]);
                racc[fi][fj] = cv;
            }
    }

#pragma unroll
    for (int fi = 0; fi < 2; ++fi)
#pragma unroll
        for (int fj = 0; fj < 2; ++fj)
            racc[fi][fj] = __builtin_amdgcn_mfma_f32_16x16x32_bf16(
                avr[fi], zv8[fj], racc[fi][fj], 0, 0, 0);

    if constexpr (OWNED) {
#pragma unroll
        for (int fi = 0; fi < 2; ++fi)
#pragma unroll
            for (int fj = 0; fj < 2; ++fj)
                (*carryc)[fi][fj] = racc[fi][fj];
    }

    if (!last) {
#pragma unroll
        for (int fj = 0; fj < 2; ++fj)
            if (pv[fj]) {
                int tr = pl[fj] - tog;
#pragma unroll
                for (int fi = 0; fi < 2; ++fi) {
                    short4_t sv;
#pragma unroll
                    for (int e = 0; e < 4; ++e) sv[e] = f2bf(racc[fi][fj][e]);
                    *(short4_t*)(tw + tswz(tr, fi * 32 + g14 * 8)) = sv;
                }
            }
    } else {
        if constexpr (OWNED) {
#pragma unroll
            for (int fj = 0; fj < 2; ++fj)
                if (pv[fj]) {
#pragma unroll
                    for (int fi = 0; fi < 2; ++fi) {
                        *(f32x4*)(hfo + pl[fj] * 32 + fi * 16 + g14 * 4) = racc[fi][fj];
                        short4_t sv;
#pragma unroll
                        for (int e = 0; e < 4; ++e) sv[e] = f2bf(racc[fi][fj][e]);
                        *(short4_t*)(hbo + pl[fj] * 32 + fi * 16 + g14 * 4) = sv;
                    }
                }
        }
    }
}

template<int LC, int S, int TH, int NTB>
__global__ __launch_bounds__(256, 2) void k_fused(
    const float* __restrict__ hfin, const short* __restrict__ hbin,
    float* __restrict__ hfout, short* __restrict__ hbout,
    const short* __restrict__ wAg, const short* __restrict__ wRg,
    short* __restrict__ Z, int li0, int pminIn, int hsum, int segbase)
{
    constexpr int TROWS = TH + S;
    constexpr int OPW = S / 128;
    __shared__ short tile[NTB][TROWS][32];

    const int lane = threadIdx.x & 63;
    const int w    = threadIdx.x >> 6;
    const int r = lane & 15, g14 = lane >> 4;
    const int b = blockIdx.y;
    const int seg0 = segbase + blockIdx.x * S;
    const int tog  = seg0 - TH;

    const float* hfb = hfin + (size_t)b * SEQ * RES_CH;
    const short* hbb = hbin + (size_t)b * SEQ * RES_CH;
    float* hfo = hfout + (size_t)b * SEQ * RES_CH;
    short* hbo = hbout + (size_t)b * SEQ * RES_CH;
    short* zbb = Z + (size_t)b * OUTLEN * QTOT;

    f32x4 carry[OPW][2][2];
    int Ht = hsum, pmt = pminIn;

#pragma unroll 1
    for (int t = 0; t < LC; ++t) {
        const int d = 1 << ((li0 + t) % 10);
        Ht -= d; pmt += d;
        const bool bglob = (t == 0);
        const bool last  = (t == LC - 1);
        const short* wAl = wAg + (li0 + t) * 4096;
        const short* wRl = wRg + (li0 + t) * 1024;
        const int liq = (li0 + t) * DIL_CH;
        char* tw = (char*)&tile[t & (NTB - 1)][0][0];
        const char* trd = (const char*)&tile[(t + NTB - 1) & (NTB - 1)][0][0];

        bf16x8 av[4][2];
#pragma unroll
        for (int fi = 0; fi < 4; ++fi)
#pragma unroll
            for (int kt = 0; kt < 2; ++kt)
                av[fi][kt] = *(const bf16x8*)(wAl + (fi * 16 + r) * 64 + kt * 32 + g14 * 8);
        bf16x8 avr[2];
#pragma unroll
        for (int fi = 0; fi < 2; ++fi)
            avr[fi] = *(const bf16x8*)(wRl + (fi * 16 + r) * 32 + g14 * 8);

#pragma unroll
        for (int oc = 0; oc < OPW; ++oc) {
            const int cp0 = seg0 + (oc * 4 + w) * 32;
            chunk_body<true>(cp0, bglob, last, d, tog, hbb, hfb, hfo, hbo,
                             zbb, liq, trd, tw, av, avr, &carry[oc], r, g14);
        }
        int lo = seg0 - Ht; if (lo < pmt) lo = pmt;
        const int nh = (seg0 - lo + 31) >> 5;
#pragma unroll 2
        for (int hc = w; hc < nh; hc += 4) {
            const int cp0 = seg0 - (hc + 1) * 32;
            chunk_body<false>(cp0, bglob, last, d, tog, hbb, hfb, hfo, hbo,
                              zbb, liq, trd, tw, av, avr, nullptr, r, g14);
        }
        __syncthreads();
    }
}

// ---------------- skip GEMM (m97 + 16B-block XOR swizzle) ----------------
__global__ __launch_bounds__(256) void k_skip_m97(
    const short* __restrict__ Z, const short* __restrict__ wskB,
    short* __restrict__ skipb)
{
    __shared__ short At[2][128 * 32];
    __shared__ short Bt[2][128 * 32];

    const int bid = blockIdx.x;          // 1024 blocks
    const int b    = bid & 7;            // one batch per XCD
    const int rest = bid >> 3;
    const int sb   = rest & 3;
    const int pb   = rest >> 2;
    const int s0   = sb * 128;
    const int p0   = pb * 128;

    const int lane = threadIdx.x & 63;
    const int w    = threadIdx.x >> 6;
    const int r = lane & 15, g14 = lane >> 4;
    const int soff = (w >> 1) * 64;
    const int poff = (w & 1) * 64;

    const short* Ab = wskB + (size_t)s0 * QTOT;
    const short* Bb = Z + ((size_t)b * OUTLEN + p0) * QTOT;

    const int rb = w * 32;
    const int l4 = lane >> 2;
    const int c4 = lane & 3;
    const int csw = c4 ^ ((l4 >> 1) & 3);       // swizzled source 16B-block
    const int rsw = (g14 ^ ((r >> 1) & 3)) * 8; // swizzled read offset (shorts)

#define SK_STAGE(bf, kt)                                                      \
    {                                                                         \
        _Pragma("unroll") for (int j = 0; j < 2; ++j) {                       \
            const short* ga = Ab + (size_t)(rb + j * 16 + l4) * QTOT          \
                                 + (kt) * 32 + csw * 8;                       \
            GLOAD_LDS16(ga, &At[bf][(rb + j * 16) * 32]);                     \
            const short* gb = Bb + (size_t)(rb + j * 16 + l4) * QTOT          \
                                 + (kt) * 32 + csw * 8;                       \
            GLOAD_LDS16(gb, &Bt[bf][(rb + j * 16) * 32]);                     \
        }                                                                     \
    }

    f32x4 acc[4][4];
    const f32x4 zero4 = {0.f, 0.f, 0.f, 0.f};
#pragma unroll
    for (int fi = 0; fi < 4; ++fi)
#pragma unroll
        for (int fj = 0; fj < 4; ++fj) acc[fi][fj] = zero4;

    SK_STAGE(0, 0)
    __syncthreads();

    int cur = 0;
#pragma unroll 1
    for (int kt = 0; kt < QTOT / 32; ++kt) {
        if (kt + 1 < QTOT / 32) SK_STAGE(cur ^ 1, kt + 1)

        bf16x8 av[4], bv[4];
#pragma unroll
        for (int fi = 0; fi < 4; ++fi)
            av[fi] = *(const bf16x8*)&At[cur][(soff + fi * 16 + r) * 32 + rsw];
#pragma unroll
        for (int fj = 0; fj < 4; ++fj)
            bv[fj] = *(const bf16x8*)&Bt[cur][(poff + fj * 16 + r) * 32 + rsw];

#pragma unroll
        for (int fi = 0; fi < 4; ++fi)
#pragma unroll
            for (int fj = 0; fj < 4; ++fj)
                acc[fi][fj] = __builtin_amdgcn_mfma_f32_16x16x32_bf16(
                    av[fi], bv[fj], acc[fi][fj], 0, 0, 0);

        __syncthreads();
        cur ^= 1;
    }

    short* skb = skipb + (size_t)b * OUTLEN * SKIP_CH;
#pragma unroll
    for (int fj = 0; fj < 4; ++fj) {
        int p = p0 + poff + fj * 16 + r;
#pragma unroll
        for (int fi = 0; fi < 4; ++fi) {
            int s = s0 + soff + fi * 16 + g14 * 4;
            short4_t v;
#pragma unroll
            for (int e = 0; e < 4; ++e) v[e] = f2bf(fmaxf(acc[fi][fj][e], 0.f));
            *(short4_t*)(skb + (size_t)p * SKIP_CH + s) = v;
        }
    }
}

// ---------------- end GEMM (same structure, K=512, f32 out + bias) --------
__global__ __launch_bounds__(256) void k_end_m97(
    const short* __restrict__ skipB, const short* __restrict__ ewB,
    const float* __restrict__ eb, float* __restrict__ out)
{
    __shared__ short At[2][128 * 32];
    __shared__ short Bt[2][128 * 32];

    const int bid = blockIdx.x;          // 512 blocks
    const int b    = bid & 7;
    const int rest = bid >> 3;           // 0..63
    const int cb   = rest & 1;
    const int pb   = rest >> 1;          // 0..31
    const int c0   = cb * 128;
    const int p0   = pb * 128;

    const int lane = threadIdx.x & 63;
    const int w    = threadIdx.x >> 6;
    const int r = lane & 15, g14 = lane >> 4;
    const int soff = (w >> 1) * 64;
    const int poff = (w & 1) * 64;

    const short* Ab = ewB + (size_t)c0 * SKIP_CH;
    const short* Bb = skipB + ((size_t)b * OUTLEN + p0) * SKIP_CH;

    const int rb = w * 32;
    const int l4 = lane >> 2;
    const int c4 = lane & 3;
    const int csw = c4 ^ ((l4 >> 1) & 3);
    const int rsw = (g14 ^ ((r >> 1) & 3)) * 8;

#define EK_STAGE(bf, kt)                                                      \
    {                                                                         \
        _Pragma("unroll") for (int j = 0; j < 2; ++j) {                       \
            const short* ga = Ab + (size_t)(rb + j * 16 + l4) * SKIP_CH       \
                                 + (kt) * 32 + csw * 8;                       \
            GLOAD_LDS16(ga, &At[bf][(rb + j * 16) * 32]);                     \
            const short* gb = Bb + (size_t)(rb + j * 16 + l4) * SKIP_CH       \
                                 + (kt) * 32 + csw * 8;                       \
            GLOAD_LDS16(gb, &Bt[bf][(rb + j * 16) * 32]);                     \
        }                                                                     \
    }

    f32x4 acc[4][4];
    const f32x4 zero4 = {0.f, 0.f, 0.f, 0.f};
#pragma unroll
    for (int fi = 0; fi < 4; ++fi)
#pragma unroll
        for (int fj = 0; fj < 4; ++fj) acc[fi][fj] = zero4;

    EK_STAGE(0, 0)
    __syncthreads();

    int cur = 0;
#pragma unroll 1
    for (int kt = 0; kt < SKIP_CH / 32; ++kt) {
        if (kt + 1 < SKIP_CH / 32) EK_STAGE(cur ^ 1, kt + 1)

        bf16x8 av[4], bv[4];
#pragma unroll
        for (int fi = 0; fi < 4; ++fi)
            av[fi] = *(const bf16x8*)&At[cur][(soff + fi * 16 + r) * 32 + rsw];
#pragma unroll
        for (int fj = 0; fj < 4; ++fj)
            bv[fj] = *(const bf16x8*)&Bt[cur][(poff + fj * 16 + r) * 32 + rsw];

#pragma unroll
        for (int fi = 0; fi < 4; ++fi)
#pragma unroll
            for (int fj = 0; fj < 4; ++fj)
                acc[fi][fj] = __builtin_amdgcn_mfma_f32_16x16x32_bf16(
                    av[fi], bv[fj], acc[fi][fj], 0, 0, 0);

        __syncthreads();
        cur ^= 1;
    }

#pragma unroll
    for (int fj = 0; fj < 4; ++fj) {
        int p = p0 + poff + fj * 16 + r;
#pragma unroll
        for (int fi = 0; fi < 4; ++fi) {
            int cls = c0 + soff + fi * 16 + g14 * 4;
            f32x4 bias = *(const f32x4*)(eb + cls);
            f32x4 v;
#pragma unroll
            for (int e = 0; e < 4; ++e) v[e] = acc[fi][fj][e] + bias[e];
            *(f32x4*)(out + ((size_t)b * OUTLEN + p) * CLASSES + cls) = v;
        }
    }
}

extern "C" void kernel_launch(void* const* d_in, const int* in_sizes, int n_in,
                              void* d_out, int out_size, void* d_ws, size_t ws_size,
                              hipStream_t stream) {
    const float* x   = (const float*)d_in[0];
    const float* sw  = (const float*)d_in[1];
    const float* fw  = (const float*)d_in[2];
    const float* gw  = (const float*)d_in[3];
    const float* rw  = (const float*)d_in[4];
    const float* wsk = (const float*)d_in[5];
    const float* ew  = (const float*)d_in[6];
    const float* eb  = (const float*)d_in[7];
    float* out = (float*)d_out;

    const size_t HN = (size_t)BATCH * SEQ * RES_CH;
    float* hf0 = (float*)d_ws;
    float* hf1 = hf0 + HN;
    short* hb0 = (short*)(hf1 + HN);
    short* hb1 = hb0 + HN;
    short* Z     = hb1 + HN;
    short* skipb = Z + (size_t)BATCH * OUTLEN * QTOT;
    short* wA    = skipb + (size_t)BATCH * OUTLEN * SKIP_CH;
    short* wR    = wA + NLAYERS * 64 * 64;
    short* wskB  = wR + NLAYERS * 32 * 32;
    short* ewB   = wskB + (size_t)SKIP_CH * QTOT;

    k_prep<<<dim3(1024), 256, 0, stream>>>(x, sw, fw, gw, rw, wsk, ew,
                                           hf0, hb0, wA, wR, wskB, ewB);

    float* hf[2] = {hf0, hf1};
    short* hb[2] = {hb0, hb1};
    int cur = 0, pmin = 0;
    for (int dec = 0; dec < 4; ++dec) {
        int li0 = dec * 10;
        // group 1: d = 1..128 (8 layers), halo sum 255
        int segbase = pmin + 255;
        int nseg = (SEQ - segbase + 255) / 256;
        k_fused<8, 256, 288, 2><<<dim3(nseg, BATCH), 256, 0, stream>>>(
            hf[cur], hb[cur], hf[cur ^ 1], hb[cur ^ 1], wA, wR, Z,
            li0, pmin, 255, segbase);
        cur ^= 1; pmin = segbase;
        // group 2: d = 256, 512 (2 layers), halo sum 768
        segbase = pmin + 768;
        nseg = (SEQ - segbase + 255) / 256;
        k_fused<2, 256, 512, 1><<<dim3(nseg, BATCH), 256, 0, stream>>>(
            hf[cur], hb[cur], hf[cur ^ 1], hb[cur ^ 1], wA, wR, Z,
            li0 + 8, pmin, 768, segbase);
        cur ^= 1; pmin = segbase;
    }

    k_skip_m97<<<dim3(1024), 256, 0, stream>>>(Z, wskB, skipb);
    k_end_m97<<<dim3(512), 256, 0, stream>>>(skipb, ewB, eb, out);
}